// Round 6
// baseline (512.565 us; speedup 1.0000x reference)
//
#include <hip/hip_runtime.h>

typedef unsigned short u16;
typedef unsigned int u32;
typedef __attribute__((ext_vector_type(8))) short short8;
typedef __attribute__((ext_vector_type(4))) float f32x4;

#define NN 50000
#define EE 800000
#define EPAD (EE + 8*NN)   // max padded edges = 1,200,000

__device__ __forceinline__ float b2f(u16 u){ union{float f;u32 i;}x; x.i=((u32)u)<<16; return x.f; }
__device__ __forceinline__ u16 f2b(float f){ union{float f;u32 i;}x; x.f=f; u32 i=x.i; return (u16)((i + 0x7fffu + ((i>>16)&1u))>>16); }

// ---------- converts ----------
__global__ void k_f2b4(const float* __restrict__ x, u16* __restrict__ y, int n4){
  int i = blockIdx.x*256 + threadIdx.x;
  if (i >= n4) return;
  float4 v = ((const float4*)x)[i];
  ushort4 o; o.x=f2b(v.x); o.y=f2b(v.y); o.z=f2b(v.z); o.w=f2b(v.w);
  ((ushort4*)y)[i]=o;
}

// transpose-convert: W[k=256][N] f32 -> Wt[N][256] bf16
__global__ void k_wtr(const float* __restrict__ W, u16* __restrict__ Wt, int N){
  int i = blockIdx.x*256 + threadIdx.x;
  if (i >= 256*N) return;
  int k = i / N, n = i % N;
  Wt[(size_t)n*256 + k] = f2b(W[i]);
}

// concat-transpose: [rWo | Wo] (each [256][160]) -> Wcat_t[320][256] bf16
__global__ void k_catWoT(const float* __restrict__ rWo, const float* __restrict__ Wo, u16* __restrict__ Bct){
  int i = blockIdx.x*256 + threadIdx.x;
  if (i >= 256*320) return;
  int k = i/320, c = i%320;
  float v = (c < 160) ? rWo[k*160 + c] : Wo[k*160 + (c-160)];
  Bct[(size_t)c*256 + k] = f2b(v);
}

// ---------- CSR build (padded: each node segment rounded up to multiple of 8) ----------
__global__ void k_count(const int* __restrict__ dst, int* __restrict__ cnt){
  int i = blockIdx.x*256+threadIdx.x; if (i<EE) atomicAdd(&cnt[dst[i]],1);
}

__global__ void k_scan_blocks(const int* __restrict__ cnt, int* __restrict__ off, int* __restrict__ part, int n){
  __shared__ int ts[256];
  int t = threadIdx.x; int base = blockIdx.x*1024 + t*4;
  int c0 = (base+0<n)?((cnt[base+0]+7)&~7):0;
  int c1 = (base+1<n)?((cnt[base+1]+7)&~7):0;
  int c2 = (base+2<n)?((cnt[base+2]+7)&~7):0;
  int c3 = (base+3<n)?((cnt[base+3]+7)&~7):0;
  int s = c0+c1+c2+c3;
  ts[t]=s; __syncthreads();
  for (int d=1; d<256; d<<=1){ int v=(t>=d)?ts[t-d]:0; __syncthreads(); ts[t]+=v; __syncthreads(); }
  int ex = ts[t]-s;
  if (t==255) part[blockIdx.x]=ts[255];
  if (base+0<n) off[base+0]=ex; ex+=c0;
  if (base+1<n) off[base+1]=ex; ex+=c1;
  if (base+2<n) off[base+2]=ex; ex+=c2;
  if (base+3<n) off[base+3]=ex;
}

__global__ void k_scan_part(int* part, int nb){
  if (threadIdx.x==0 && blockIdx.x==0){ int run=0; for(int i=0;i<nb;++i){ int v=part[i]; part[i]=run; run+=v; } }
}

// addback and also initialize cur = off
__global__ void k_addback(int* off, int* cur, const int* __restrict__ part, int n){
  int base = blockIdx.x*1024 + threadIdx.x*4; int p = part[blockIdx.x];
  #pragma unroll
  for (int j=0;j<4;++j) if (base+j<n){ int v = off[base+j]+p; off[base+j]=v; if (base+j<NN) cur[base+j]=v; }
}

__global__ void k_scatter(const int* __restrict__ src, const int* __restrict__ dst, int* __restrict__ cur,
                          int* __restrict__ srcs){
  int i = blockIdx.x*256+threadIdx.x; if (i>=EE) return;
  int d = dst[i]; int p = atomicAdd(&cur[d],1);
  srcs[p]=src[i];
}

// ---------- GEMM2: C[M,:] = A[M,256](bf16) @ Bt[N,256]^T, f32 acc ----------
// BM=128, full-K LDS stage via global_load_lds (pre-swizzled source), 256 thr = 4 waves (2Mx2N)
// MODE 0: f32 out. MODE 1: bf16 out + fused el/er epilogue (64-dim heads). MODE 2: split 160/160 bf16.
template<int BN, int MODE>
__global__ __launch_bounds__(256) void k_gemm2(const u16* __restrict__ A, const u16* __restrict__ Bt,
                                               void* __restrict__ C0, void* __restrict__ C1,
                                               const float* __restrict__ AL, const float* __restrict__ AR,
                                               float* __restrict__ EL, float* __restrict__ ER,
                                               int M, int ldC){
  __shared__ u16 lds[(128+BN)*256];
  u16* As = lds;
  u16* Bs = lds + 128*256;
  const int tid = threadIdx.x;
  const int row0 = blockIdx.x * 128;
  const int n0   = blockIdx.y * BN;
  #pragma unroll
  for (int it=0; it<16; ++it){
    int slot = it*256 + tid;
    int r = slot >> 5, s = slot & 31;
    int gs = s ^ (r & 7);
    const u16* gp = A + (size_t)(row0 + r)*256 + (gs<<3);
    u16* lp = As + (size_t)(it*256 + (tid & ~63))*8;
    __builtin_amdgcn_global_load_lds((const void*)gp, (void*)lp, 16, 0, 0);
  }
  #pragma unroll
  for (int it=0; it<BN/8; ++it){
    int slot = it*256 + tid;
    int r = slot >> 5, s = slot & 31;
    int gs = s ^ (r & 7);
    const u16* gp = Bt + (size_t)(n0 + r)*256 + (gs<<3);
    u16* lp = Bs + (size_t)(it*256 + (tid & ~63))*8;
    __builtin_amdgcn_global_load_lds((const void*)gp, (void*)lp, 16, 0, 0);
  }
  __syncthreads();
  const int wave = tid >> 6, l = tid & 63;
  const int wm = wave >> 1, wn = wave & 1;
  const int lr = l & 15, lq = l >> 4;
  const int NR = BN/32;
  f32x4 acc[4][4];
  #pragma unroll
  for (int mr=0;mr<4;++mr)
    #pragma unroll
    for (int nr=0;nr<NR;++nr) acc[mr][nr]=(f32x4)0.0f;
  #pragma unroll
  for (int kk=0; kk<8; ++kk){
    short8 a[4], b[4];
    #pragma unroll
    for (int mr=0;mr<4;++mr){
      int rloc = wm*64 + mr*16 + lr;
      int byo = rloc*512 + ((kk*64 + lq*16) ^ ((rloc&7)<<4));
      a[mr] = *(const short8*)((const char*)As + byo);
    }
    #pragma unroll
    for (int nr=0;nr<NR;++nr){
      int cloc = wn*(BN/2) + nr*16 + lr;
      int byo = cloc*512 + ((kk*64 + lq*16) ^ ((cloc&7)<<4));
      b[nr] = *(const short8*)((const char*)Bs + byo);
    }
    #pragma unroll
    for (int mr=0;mr<4;++mr)
      #pragma unroll
      for (int nr=0;nr<NR;++nr)
        acc[mr][nr] = __builtin_amdgcn_mfma_f32_16x16x32_bf16(a[mr], b[nr], acc[mr][nr], 0, 0, 0);
  }
  #pragma unroll
  for (int mr=0;mr<4;++mr)
    #pragma unroll
    for (int nr=0;nr<NR;++nr)
      #pragma unroll
      for (int q=0;q<4;++q){
        int r = row0 + wm*64 + mr*16 + lq*4 + q;
        if (r < M){
          int c = n0 + wn*(BN/2) + nr*16 + lr;
          float v = acc[mr][nr][q];
          if constexpr (MODE == 0)      ((float*)C0)[(size_t)r*ldC + c] = v;
          else if constexpr (MODE == 1) ((u16*)C0)[(size_t)r*ldC + c] = f2b(v);
          else {
            if (c < 160)      ((u16*)C0)[(size_t)r*160 + c]       = f2b(v);
            else if (c < 320) ((u16*)C1)[(size_t)r*160 + (c-160)] = f2b(v);
          }
        }
      }
  if constexpr (MODE == 1){
    // fused el/er: this wave's 64-col span is exactly one 64-dim head
    const int head = (n0 + wn*64) >> 6;
    float alc[4], arc[4];
    #pragma unroll
    for (int nr=0;nr<4;++nr){
      int c = n0 + wn*64 + nr*16 + lr;
      alc[nr] = AL[c]; arc[nr] = AR[c];
    }
    #pragma unroll
    for (int mr=0;mr<4;++mr)
      #pragma unroll
      for (int q=0;q<4;++q){
        float suml = acc[mr][0][q]*alc[0] + acc[mr][1][q]*alc[1] + acc[mr][2][q]*alc[2] + acc[mr][3][q]*alc[3];
        float sumr = acc[mr][0][q]*arc[0] + acc[mr][1][q]*arc[1] + acc[mr][2][q]*arc[2] + acc[mr][3][q]*arc[3];
        #pragma unroll
        for (int msk=1; msk<16; msk<<=1){ suml += __shfl_xor(suml,msk,64); sumr += __shfl_xor(sumr,msk,64); }
        int r = row0 + wm*64 + mr*16 + lq*4 + q;
        if (lr == 0 && r < M){ EL[r*4+head] = suml; ER[r*4+head] = sumr; }
      }
  }
}

// ---------- generic el/er (output layer: Dh=40, HD=160) ----------
__global__ void k_eler(const u16* __restrict__ feat, const float* __restrict__ al, const float* __restrict__ ar,
                       float* __restrict__ el, float* __restrict__ er, int Dh, int HD){
  int t = blockIdx.x*256 + threadIdx.x;
  int n = t >> 6; int l = t & 63;
  if (n >= NN) return;
  int h = l >> 4, s = l & 15;
  const u16* fr = feat + (size_t)n*HD + h*Dh;
  const float* alh = al + h*Dh; const float* arh = ar + h*Dh;
  float accl = 0.f, accr = 0.f;
  for (int d = s; d < Dh; d += 16){ float f = b2f(fr[d]); accl += f*alh[d]; accr += f*arh[d]; }
  #pragma unroll
  for (int m = 8; m >= 1; m >>= 1){ accl += __shfl_xor(accl, m, 64); accr += __shfl_xor(accr, m, 64); }
  if (s == 0){ el[n*4+h] = accl; er[n*4+h] = accr; }
}

// ---------- fused softmax prefix (wave-local): scores -> es, return rc4 ----------
__device__ __forceinline__ float4 soft_prefix(const float* __restrict__ el, float4 e4,
    const int* __restrict__ srcs, float* __restrict__ es, int o0, int o1p, int oend, int l){
  float4 m; m.x=m.y=m.z=m.w=-1e30f;
  for (int e = o0 + l; e < o1p; e += 64){
    float4 v;
    if (e < oend){
      float4 a = ((const float4*)el)[srcs[e]];
      v.x=a.x+e4.x; v.x=v.x>=0.f?v.x:0.2f*v.x;
      v.y=a.y+e4.y; v.y=v.y>=0.f?v.y:0.2f*v.y;
      v.z=a.z+e4.z; v.z=v.z>=0.f?v.z:0.2f*v.z;
      v.w=a.w+e4.w; v.w=v.w>=0.f?v.w:0.2f*v.w;
    } else { v.x=v.y=v.z=v.w=-1e30f; }
    ((float4*)es)[e] = v;
    m.x=fmaxf(m.x,v.x); m.y=fmaxf(m.y,v.y); m.z=fmaxf(m.z,v.z); m.w=fmaxf(m.w,v.w);
  }
  #pragma unroll
  for (int msk=1; msk<64; msk<<=1){
    m.x=fmaxf(m.x,__shfl_xor(m.x,msk,64)); m.y=fmaxf(m.y,__shfl_xor(m.y,msk,64));
    m.z=fmaxf(m.z,__shfl_xor(m.z,msk,64)); m.w=fmaxf(m.w,__shfl_xor(m.w,msk,64));
  }
  float4 s; s.x=s.y=s.z=s.w=0.f;
  for (int e = o0 + l; e < o1p; e += 64){
    float4 v = ((const float4*)es)[e];
    v.x=__expf(v.x-m.x); v.y=__expf(v.y-m.y); v.z=__expf(v.z-m.z); v.w=__expf(v.w-m.w);
    ((float4*)es)[e]=v;
    s.x+=v.x; s.y+=v.y; s.z+=v.z; s.w+=v.w;
  }
  #pragma unroll
  for (int msk=1; msk<64; msk<<=1){
    s.x+=__shfl_xor(s.x,msk,64); s.y+=__shfl_xor(s.y,msk,64);
    s.z+=__shfl_xor(s.z,msk,64); s.w+=__shfl_xor(s.w,msk,64);
  }
  float4 rc;
  rc.x = s.x>0.f ? 1.f/s.x : 0.f;
  rc.y = s.y>0.f ? 1.f/s.y : 0.f;
  rc.z = s.z>0.f ? 1.f/s.z : 0.f;
  rc.w = s.w>0.f ? 1.f/s.w : 0.f;
  return rc;
}

// ---------- D=64 aggregation, fused softmax; wave per node, half-wave pairs, 8-edge unroll ----------
template<bool RES>
__global__ __launch_bounds__(256) void k_agg64(const u16* __restrict__ feat,
    const float* __restrict__ el, const float* __restrict__ er, float* __restrict__ es,
    const int* __restrict__ off, const int* __restrict__ cnt, const int* __restrict__ srcs,
    const u16* __restrict__ resid, float* __restrict__ outf, u16* __restrict__ outb){
  const int l = threadIdx.x & 63, w = threadIdx.x >> 6;
  const int n = blockIdx.x*4 + w;
  const int o0 = off[n], o1p = off[n+1];
  const int oend = o0 + cnt[n];
  float4 e4 = ((const float4*)er)[n];
  float4 rc4 = soft_prefix(el, e4, srcs, es, o0, o1p, oend, l);
  const int lh = l & 31;
  const int half = l >> 5;
  const int h = lh >> 3;
  const float rch = ((const float*)&rc4)[h];
  float a0=0.f,a1=0.f,a2=0.f,a3=0.f,a4=0.f,a5=0.f,a6=0.f,a7=0.f;
  for (int i = o0; i < o1p; i += 8){
    #pragma unroll
    for (int u=0; u<4; ++u){
      int e = i + u*2 + half;
      int sv = srcs[e];
      float al = es[(size_t)e*4 + h];
      short8 f = *(const short8*)(feat + (size_t)sv*256 + lh*8);
      a0 += al*b2f((u16)f[0]); a1 += al*b2f((u16)f[1]);
      a2 += al*b2f((u16)f[2]); a3 += al*b2f((u16)f[3]);
      a4 += al*b2f((u16)f[4]); a5 += al*b2f((u16)f[5]);
      a6 += al*b2f((u16)f[6]); a7 += al*b2f((u16)f[7]);
    }
  }
  a0 += __shfl_xor(a0,32,64); a1 += __shfl_xor(a1,32,64);
  a2 += __shfl_xor(a2,32,64); a3 += __shfl_xor(a3,32,64);
  a4 += __shfl_xor(a4,32,64); a5 += __shfl_xor(a5,32,64);
  a6 += __shfl_xor(a6,32,64); a7 += __shfl_xor(a7,32,64);
  if (half == 0){
    float v[8] = {a0*rch,a1*rch,a2*rch,a3*rch,a4*rch,a5*rch,a6*rch,a7*rch};
    if (RES){
      short8 r8 = *(const short8*)(resid + (size_t)n*256 + lh*8);
      #pragma unroll
      for (int j=0;j<8;++j) v[j] += b2f((u16)r8[j]);
    }
    #pragma unroll
    for (int j=0;j<8;++j) v[j] = v[j] > 0.f ? v[j] : expm1f(v[j]);
    if (outf){
      float4 q0; q0.x=v[0]; q0.y=v[1]; q0.z=v[2]; q0.w=v[3];
      float4 q1; q1.x=v[4]; q1.y=v[5]; q1.z=v[6]; q1.w=v[7];
      *(float4*)(outf + (size_t)n*256 + lh*8)     = q0;
      *(float4*)(outf + (size_t)n*256 + lh*8 + 4) = q1;
    }
    short8 ob;
    #pragma unroll
    for (int j=0;j<8;++j) ob[j] = (short)f2b(v[j]);
    *(short8*)(outb + (size_t)n*256 + lh*8) = ob;
  }
}

// ---------- output-layer aggregation, fused softmax: 8-edge groups, ushort8 loads ----------
__global__ __launch_bounds__(256) void k_agg_out(const u16* __restrict__ feat,
    const float* __restrict__ el, const float* __restrict__ er, float* __restrict__ es,
    const int* __restrict__ off, const int* __restrict__ cnt, const int* __restrict__ srcs,
    const u16* __restrict__ reso, float* __restrict__ logits){
  __shared__ float red[4][8][20][8];
  __shared__ float fin[4][160];
  const int l = threadIdx.x & 63, w = threadIdx.x >> 6;
  const int n = blockIdx.x*4 + w;
  const int o0 = off[n], o1p = off[n+1];
  const int oend = o0 + cnt[n];
  float4 e4 = ((const float4*)er)[n];
  float4 rc4 = soft_prefix(el, e4, srcs, es, o0, o1p, oend, l);
  const int s0 = l/20,        q0 = l%20;
  const int s1 = (64+l)/20,   q1 = (64+l)%20;
  const int s2 = (128+l)/20,  q2 = (128+l)%20;   // active l<32
  const int h0 = q0/5, h1 = q1/5, h2 = q2/5;
  float acc0[8], acc1[8], acc2[8];
  #pragma unroll
  for (int j=0;j<8;++j){ acc0[j]=0.f; acc1[j]=0.f; acc2[j]=0.f; }
  for (int i0 = o0; i0 < o1p; i0 += 8){
    {
      int e = i0 + s0; int sv = srcs[e]; float al = es[(size_t)e*4 + h0];
      short8 f = *(const short8*)(feat + (size_t)sv*160 + q0*8);
      #pragma unroll
      for (int j=0;j<8;++j) acc0[j] += al*b2f((u16)f[j]);
    }
    {
      int e = i0 + s1; int sv = srcs[e]; float al = es[(size_t)e*4 + h1];
      short8 f = *(const short8*)(feat + (size_t)sv*160 + q1*8);
      #pragma unroll
      for (int j=0;j<8;++j) acc1[j] += al*b2f((u16)f[j]);
    }
    if (l < 32){
      int e = i0 + s2; int sv = srcs[e]; float al = es[(size_t)e*4 + h2];
      short8 f = *(const short8*)(feat + (size_t)sv*160 + q2*8);
      #pragma unroll
      for (int j=0;j<8;++j) acc2[j] += al*b2f((u16)f[j]);
    }
  }
  #pragma unroll
  for (int j=0;j<8;++j) red[w][s0][q0][j] = acc0[j];
  #pragma unroll
  for (int j=0;j<8;++j) red[w][s1][q1][j] = acc1[j];
  if (l < 32){
    #pragma unroll
    for (int j=0;j<8;++j) red[w][s2][q2][j] = acc2[j];
  }
  __syncthreads();
  if (l < 20){
    const int q = l;
    float rc = ((const float*)&rc4)[q/5];
    short8 rr = *(const short8*)(reso + (size_t)n*160 + q*8);
    #pragma unroll
    for (int j=0;j<8;++j){
      float v = red[w][0][q][j];
      #pragma unroll
      for (int s=1;s<8;++s) v += red[w][s][q][j];
      fin[w][q*8+j] = v*rc + b2f((u16)rr[j]);
    }
  }
  __syncthreads();
  if (l < 40) logits[(size_t)n*40 + l] = 0.25f*(fin[w][l]+fin[w][l+40]+fin[w][l+80]+fin[w][l+120]);
}

extern "C" void kernel_launch(void* const* d_in, const int* in_sizes, int n_in,
                              void* d_out, int out_size, void* d_ws, size_t ws_size,
                              hipStream_t stream){
  const float* inputs = (const float*)d_in[0];
  const int*   src    = (const int*)d_in[1];
  const int*   dst    = (const int*)d_in[2];
  const float* W0  = (const float*)d_in[3];
  const float* al0 = (const float*)d_in[4];
  const float* ar0 = (const float*)d_in[5];
  const float* W1  = (const float*)d_in[6];
  const float* al1 = (const float*)d_in[7];
  const float* ar1 = (const float*)d_in[8];
  const float* Wo  = (const float*)d_in[9];
  const float* alo = (const float*)d_in[10];
  const float* aro = (const float*)d_in[11];
  const float* rWo = (const float*)d_in[12];
  const float* fcW = (const float*)d_in[13];

  float* out = (float*)d_out;
  float* out_logits = out;                 // [50000,40]
  float* out_h      = out + 2000000;       // [50000,256]
  float* out_seq    = out + 14800000;      // [50000,64]

  char* ws = (char*)d_ws;
  size_t o = 0;
  auto alc = [&](size_t bytes){ size_t r = o; o += (bytes + 255) & ~(size_t)255; return r; };
  size_t oXb   = alc((size_t)NN*256*2);
  size_t oFA   = alc((size_t)NN*256*2);
  size_t oFB   = alc((size_t)NN*256*2);
  size_t oEs   = alc((size_t)EPAD*4*4);
  size_t oSrcs = alc((size_t)EPAD*4);
  size_t oOff  = alc((size_t)(NN+1)*4);
  size_t oCnt  = alc((size_t)(NN+1)*4);
  size_t oCur  = alc((size_t)NN*4);
  size_t oPart = alc(64*4);
  size_t oEl   = alc((size_t)NN*4*4);
  size_t oEr   = alc((size_t)NN*4*4);
  size_t oReso = alc((size_t)NN*160*2);
  size_t oW0t  = alc(256*256*2);
  size_t oW1t  = alc(256*256*2);
  size_t oWct  = alc((size_t)384*256*2);
  size_t oFct  = alc((size_t)128*256*2);
  if (ws_size < o) return;

  u16* Xb   = (u16*)(ws + oXb);
  u16* fA   = (u16*)(ws + oFA);
  u16* fB   = (u16*)(ws + oFB);
  float* es = (float*)(ws + oEs);
  int* srcs = (int*)(ws + oSrcs);
  int* off  = (int*)(ws + oOff);
  int* cnt  = (int*)(ws + oCnt);
  int* cur  = (int*)(ws + oCur);
  int* part = (int*)(ws + oPart);
  float* el = (float*)(ws + oEl);
  float* er = (float*)(ws + oEr);
  u16* reso = (u16*)(ws + oReso);
  u16* W0t  = (u16*)(ws + oW0t);
  u16* W1t  = (u16*)(ws + oW1t);
  u16* Wct  = (u16*)(ws + oWct);
  u16* fct  = (u16*)(ws + oFct);

  // ---- converts (weights transposed for GEMM2 B-staging) ----
  k_f2b4<<<(NN*256/4 + 255)/256, 256, 0, stream>>>(inputs, Xb, NN*256/4);
  k_wtr<<<(256*256 + 255)/256, 256, 0, stream>>>(W0, W0t, 256);
  k_wtr<<<(256*256 + 255)/256, 256, 0, stream>>>(W1, W1t, 256);
  k_wtr<<<(256*64 + 255)/256, 256, 0, stream>>>(fcW, fct, 64);
  k_catWoT<<<(256*320 + 255)/256, 256, 0, stream>>>(rWo, Wo, Wct);

  // ---- CSR (padded) ----
  hipMemsetAsync(cnt, 0, (size_t)(NN+1)*4, stream);
  hipMemsetAsync(srcs, 0, (size_t)EPAD*4, stream);
  k_count<<<(EE+255)/256, 256, 0, stream>>>(dst, cnt);
  const int NP1 = NN+1, NB = (NP1 + 1023)/1024;
  k_scan_blocks<<<NB, 256, 0, stream>>>(cnt, off, part, NP1);
  k_scan_part<<<1, 64, 0, stream>>>(part, NB);
  k_addback<<<NB, 256, 0, stream>>>(off, cur, part, NP1);
  k_scatter<<<(EE+255)/256, 256, 0, stream>>>(src, dst, cur, srcs);

  const int GX = (NN + 127)/128;   // 391
  dim3 g256(GX, 2), g320(GX, 3), g64(GX, 1);

  // ---- seq_fts = X @ fc_W (f32 out) ----
  k_gemm2<64,0><<<g64, 256, 0, stream>>>(Xb, fct, out_seq, nullptr, nullptr, nullptr, nullptr, nullptr, NN, 64);

  // ---- layer 0: GEMM(+el/er) -> agg(+softmax) ----
  k_gemm2<128,1><<<g256, 256, 0, stream>>>(Xb, W0t, fA, nullptr, al0, ar0, el, er, NN, 256);
  k_agg64<false><<<NN/4, 256, 0, stream>>>(fA, el, er, es, off, cnt, srcs, nullptr, nullptr, fB);

  // ---- layer 1 ----
  k_gemm2<128,1><<<g256, 256, 0, stream>>>(fB, W1t, fA, nullptr, al1, ar1, el, er, NN, 256);
  k_agg64<true><<<NN/4, 256, 0, stream>>>(fA, el, er, es, off, cnt, srcs, fB, out_h, fB);

  // ---- output layer: fused [reso | Wo] GEMM -> eler -> agg(+softmax) ----
  k_gemm2<128,2><<<g320, 256, 0, stream>>>(fB, Wct, reso, fA, nullptr, nullptr, nullptr, nullptr, NN, 320);
  k_eler<<<(NN*64 + 255)/256, 256, 0, stream>>>(fA, alo, aro, el, er, 40, 160);
  k_agg_out<<<NN/4, 256, 0, stream>>>(fA, el, er, es, off, cnt, srcs, reso, out_logits);
}